// Round 1
// 1129.851 us; speedup vs baseline: 1.1558x; 1.1558x over previous
//
#include <hip/hip_runtime.h>
#include <math.h>

namespace {

constexpr int S_ = 1024;
constexpr int B_ = 64;
constexpr int D_ = 64;
constexpr float SCALE = 0.125f;  // 1/sqrt(64)

typedef __attribute__((ext_vector_type(8))) short bf16x8;
typedef __attribute__((ext_vector_type(4))) float f32x4;

__device__ __forceinline__ ushort f2bf(float x) {
  union { float f; uint u; } c; c.f = x;
  return (ushort)((c.u + 0x7fffu + ((c.u >> 16) & 1u)) >> 16);  // RNE
}
__device__ __forceinline__ float bf2f(ushort h) {
  union { uint u; float f; } c; c.u = ((uint)h) << 16;
  return c.f;
}

// XOR swizzle for [row][64] bf16 LDS tiles: spreads the stride-128B rows
// across banks so ds_read_b128 fragment loads are conflict-free-ish.
#define SWZ(row, c) (((row) << 6) + ((c) ^ (((row) & 7) << 3)))

#define MFMA(a, b, c) __builtin_amdgcn_mfma_f32_16x16x32_bf16((a), (b), (c), 0, 0, 0)

// ---------------------------------------------------------------------------
// Kernel A: bias[b,qp,k] = sum_d Q[b,qp,d] * R_k[qp,k,d]   (only k <= qp)
// MFMA: A = Q[batch, d] (bf16), B = R_k[qp][k, d] (bf16). Error ~5e-5 logit.
// Grid: (4 k-chunks of 256, S qp).  Block: 256 threads (4 waves, 16 b-rows each).
// ---------------------------------------------------------------------------
__global__ __launch_bounds__(256) void bias_kernel(
    const float* __restrict__ q, const float* __restrict__ Rk,
    float* __restrict__ attn) {
  const int qp = (S_ - 1) - (int)blockIdx.y;  // big rows first
  const int chunk = blockIdx.x;
  if (chunk * 256 > qp) return;  // uniform exit

  __shared__ __align__(16) ushort Rh[64 * 64];

  const int t = threadIdx.x;
  const int wid = t >> 6, lane = t & 63;
  const int llo = lane & 15, lhi = lane >> 4;
  const f32x4 fz = {0.f, 0.f, 0.f, 0.f};

  // Q fragments: A rows = batch index = wid*16 + llo
  bf16x8 qa[2];
  {
    const int brow = wid * 16 + llo;
    const float* qp_ = q + (((brow << 10) + qp) << 6) + lhi * 8;
    #pragma unroll
    for (int s = 0; s < 2; ++s)
      #pragma unroll
      for (int j = 0; j < 8; ++j) qa[s][j] = (short)f2bf(qp_[s * 32 + j]);
  }

  for (int s4 = 0; s4 < 4; ++s4) {
    const int kb = chunk * 256 + s4 * 64;
    if (kb > qp) break;  // uniform
    __syncthreads();
    #pragma unroll
    for (int i = 0; i < 4; ++i) {
      const int flat = t + i * 256;
      const int kk = flat >> 4, dd = (flat & 15) * 4;
      const float4 r4 = *(const float4*)(Rk + (((qp << 10) + kb + kk) << 6) + dd);
      *(ushort4*)&Rh[SWZ(kk, dd)] =
          make_ushort4(f2bf(r4.x), f2bf(r4.y), f2bf(r4.z), f2bf(r4.w));
    }
    __syncthreads();

    f32x4 acc[4];
    #pragma unroll
    for (int kt = 0; kt < 4; ++kt) acc[kt] = fz;
    #pragma unroll
    for (int s = 0; s < 2; ++s)
      #pragma unroll
      for (int kt = 0; kt < 4; ++kt) {
        const bf16x8 rb =
            *(const bf16x8*)&Rh[SWZ(kt * 16 + llo, s * 32 + lhi * 8)];
        acc[kt] = MFMA(qa[s], rb, acc[kt]);
      }

    #pragma unroll
    for (int r = 0; r < 4; ++r) {
      const int bb = wid * 16 + lhi * 4 + r;
      float* row = attn + (((bb << 10) + qp) << 10) + kb + llo;
      #pragma unroll
      for (int kt = 0; kt < 4; ++kt)
        if (kb + kt * 16 + llo <= qp) row[kt * 16] = acc[kt][r];
    }
  }
}

// ---------------------------------------------------------------------------
// Kernel B: per (b, 64-row q tile): scores = (QK^T + bias)*SCALE via
// split-bf16 MFMA (qh*kh + ql*kh + qh*kl, fp32-accurate), two-pass causal
// softmax with bit-identical score recompute, attn write (in place over the
// bias scratch), PV via bf16 MFMA.  Grid: (16 q-tiles, 64 b).  Block: 256.
// ---------------------------------------------------------------------------
__global__ __launch_bounds__(256) void attn_kernel(
    const float* __restrict__ qg, const float* __restrict__ kg,
    const float* __restrict__ vg, float* attn, float* __restrict__ outg) {
  const int b = blockIdx.y;
  const int qti = 15 - (int)blockIdx.x;  // big tiles first
  const int qb = qti * 64;
  const int ntiles = qti + 1;

  __shared__ __align__(16) ushort Khi[64 * 64];
  __shared__ __align__(16) ushort Klo[64 * 64];
  __shared__ __align__(16) ushort VT[64 * 64];    // V transposed [d][k]
  __shared__ __align__(16) ushort Pl[4 * 16 * 64];  // per-wave P tile

  const int t = threadIdx.x;
  const int wid = t >> 6, lane = t & 63;
  const int llo = lane & 15, lhi = lane >> 4;
  const f32x4 fz = {0.f, 0.f, 0.f, 0.f};

  // Q fragments (split hi/lo): A rows = q rows = qb + wid*16 + llo
  bf16x8 qh[2], ql[2];
  {
    const int qrow = qb + wid * 16 + llo;
    const float* qp_ = qg + (((b << 10) + qrow) << 6) + lhi * 8;
    #pragma unroll
    for (int s = 0; s < 2; ++s)
      #pragma unroll
      for (int j = 0; j < 8; ++j) {
        const float x = qp_[s * 32 + j];
        const ushort h = f2bf(x);
        qh[s][j] = (short)h;
        ql[s][j] = (short)f2bf(x - bf2f(h));
      }
  }

  float m[4], l[4];
  #pragma unroll
  for (int r = 0; r < 4; ++r) { m[r] = -INFINITY; l[r] = 0.f; }

  // ---------------- pass 1: row max & sum of exp ----------------
  for (int tt = 0; tt < ntiles; ++tt) {
    const int kb = tt * 64;
    __syncthreads();
    #pragma unroll
    for (int i = 0; i < 4; ++i) {
      const int flat = t + i * 256;
      const int kk = flat >> 4, dd = (flat & 15) * 4;
      const float4 r4 = *(const float4*)(kg + (((b << 10) + kb + kk) << 6) + dd);
      const ushort h0 = f2bf(r4.x), h1 = f2bf(r4.y);
      const ushort h2 = f2bf(r4.z), h3 = f2bf(r4.w);
      const int idx = SWZ(kk, dd);
      *(ushort4*)&Khi[idx] = make_ushort4(h0, h1, h2, h3);
      *(ushort4*)&Klo[idx] = make_ushort4(
          f2bf(r4.x - bf2f(h0)), f2bf(r4.y - bf2f(h1)),
          f2bf(r4.z - bf2f(h2)), f2bf(r4.w - bf2f(h3)));
    }
    __syncthreads();

    f32x4 acc[4];
    #pragma unroll
    for (int kt = 0; kt < 4; ++kt) acc[kt] = fz;
    #pragma unroll
    for (int s = 0; s < 2; ++s)
      #pragma unroll
      for (int kt = 0; kt < 4; ++kt) {
        const int o = SWZ(kt * 16 + llo, s * 32 + lhi * 8);
        const bf16x8 kh = *(const bf16x8*)&Khi[o];
        const bf16x8 kl = *(const bf16x8*)&Klo[o];
        acc[kt] = MFMA(qh[s], kh, acc[kt]);
        acc[kt] = MFMA(ql[s], kh, acc[kt]);
        acc[kt] = MFMA(qh[s], kl, acc[kt]);
      }

    #pragma unroll
    for (int r = 0; r < 4; ++r) {
      const int qq = qb + wid * 16 + lhi * 4 + r;
      const float* bp = attn + (((b << 10) + qq) << 10) + kb + llo;
      float sv[4];
      float tmax = -INFINITY;
      #pragma unroll
      for (int kt = 0; kt < 4; ++kt) {
        const float s = (acc[kt][r] + bp[kt * 16]) * SCALE;
        sv[kt] = s;
        if (kb + kt * 16 + llo <= qq) tmax = fmaxf(tmax, s);
      }
      tmax = fmaxf(tmax, __shfl_xor(tmax, 1));
      tmax = fmaxf(tmax, __shfl_xor(tmax, 2));
      tmax = fmaxf(tmax, __shfl_xor(tmax, 4));
      tmax = fmaxf(tmax, __shfl_xor(tmax, 8));
      const float mnew = fmaxf(m[r], tmax);
      const float corr = __expf(m[r] - mnew);
      float ladd = 0.f;
      #pragma unroll
      for (int kt = 0; kt < 4; ++kt)
        if (kb + kt * 16 + llo <= qq) ladd += __expf(sv[kt] - mnew);
      l[r] = l[r] * corr + ladd;
      m[r] = mnew;
    }
  }

  // reduce l across the 16 k-lanes of each group (m already common)
  float linv[4];
  #pragma unroll
  for (int r = 0; r < 4; ++r) {
    float ls = l[r];
    ls += __shfl_xor(ls, 1);
    ls += __shfl_xor(ls, 2);
    ls += __shfl_xor(ls, 4);
    ls += __shfl_xor(ls, 8);
    linv[r] = 1.f / ls;
  }

  f32x4 oacc[4];
  #pragma unroll
  for (int nt = 0; nt < 4; ++nt) oacc[nt] = fz;

  // ---------------- pass 2: write attn + accumulate PV ----------------
  for (int tt = 0; tt < ntiles; ++tt) {
    const int kb = tt * 64;
    __syncthreads();
    #pragma unroll
    for (int i = 0; i < 4; ++i) {  // K: identical to pass 1 (bit-identity)
      const int flat = t + i * 256;
      const int kk = flat >> 4, dd = (flat & 15) * 4;
      const float4 r4 = *(const float4*)(kg + (((b << 10) + kb + kk) << 6) + dd);
      const ushort h0 = f2bf(r4.x), h1 = f2bf(r4.y);
      const ushort h2 = f2bf(r4.z), h3 = f2bf(r4.w);
      const int idx = SWZ(kk, dd);
      *(ushort4*)&Khi[idx] = make_ushort4(h0, h1, h2, h3);
      *(ushort4*)&Klo[idx] = make_ushort4(
          f2bf(r4.x - bf2f(h0)), f2bf(r4.y - bf2f(h1)),
          f2bf(r4.z - bf2f(h2)), f2bf(r4.w - bf2f(h3)));
    }
    #pragma unroll
    for (int i = 0; i < 4; ++i) {  // V, transposed into VT[d][k]
      const int kk = lane;
      const int dd = (wid + i * 4) * 4;
      const float4 r4 = *(const float4*)(vg + (((b << 10) + kb + kk) << 6) + dd);
      VT[SWZ(dd + 0, kk)] = f2bf(r4.x);
      VT[SWZ(dd + 1, kk)] = f2bf(r4.y);
      VT[SWZ(dd + 2, kk)] = f2bf(r4.z);
      VT[SWZ(dd + 3, kk)] = f2bf(r4.w);
    }
    __syncthreads();

    f32x4 acc[4];
    #pragma unroll
    for (int kt = 0; kt < 4; ++kt) acc[kt] = fz;
    #pragma unroll
    for (int s = 0; s < 2; ++s)
      #pragma unroll
      for (int kt = 0; kt < 4; ++kt) {
        const int o = SWZ(kt * 16 + llo, s * 32 + lhi * 8);
        const bf16x8 kh = *(const bf16x8*)&Khi[o];
        const bf16x8 kl = *(const bf16x8*)&Klo[o];
        acc[kt] = MFMA(qh[s], kh, acc[kt]);
        acc[kt] = MFMA(ql[s], kh, acc[kt]);
        acc[kt] = MFMA(qh[s], kl, acc[kt]);
      }

    #pragma unroll
    for (int r = 0; r < 4; ++r) {
      const int qq = qb + wid * 16 + lhi * 4 + r;
      float* arow = attn + (((b << 10) + qq) << 10) + kb + llo;
      const int prow = lhi * 4 + r;
      #pragma unroll
      for (int kt = 0; kt < 4; ++kt) {
        const float s = (acc[kt][r] + arow[kt * 16]) * SCALE;
        const float p =
            (kb + kt * 16 + llo <= qq) ? __expf(s - m[r]) * linv[r] : 0.f;
        arow[kt * 16] = p;
        Pl[(wid << 10) + SWZ(prow, kt * 16 + llo)] = f2bf(p);
      }
    }
    __syncthreads();

    #pragma unroll
    for (int s = 0; s < 2; ++s) {
      const bf16x8 pa =
          *(const bf16x8*)&Pl[(wid << 10) + SWZ(llo, s * 32 + lhi * 8)];
      #pragma unroll
      for (int nt = 0; nt < 4; ++nt) {
        const bf16x8 vb = *(const bf16x8*)&VT[SWZ(nt * 16 + llo, s * 32 + lhi * 8)];
        oacc[nt] = MFMA(pa, vb, oacc[nt]);
      }
    }
  }

  // ---------------- zero-fill attn for k >= ntiles*64 ----------------
  {
    const int k0 = (t & 15) * 4;
    const int q0 = (t >> 4) * 4;
    for (int kb = ntiles * 64; kb < S_; kb += 64) {
      #pragma unroll
      for (int j = 0; j < 4; ++j) {
        const int qq = qb + q0 + j;
        *(float4*)(attn + (((b << 10) + qq) << 10) + kb + k0) =
            make_float4(0.f, 0.f, 0.f, 0.f);
      }
    }
  }

  // ---------------- store out (already normalized) ----------------
  #pragma unroll
  for (int r = 0; r < 4; ++r) {
    const int qq = qb + wid * 16 + lhi * 4 + r;
    #pragma unroll
    for (int nt = 0; nt < 4; ++nt)
      outg[(((b << 10) + qq) << 6) + nt * 16 + llo] = oacc[nt][r];
  }
}

// ---------------------------------------------------------------------------
// Kernel C: out[b,qp,:] += sum_k attn[b,qp,k] * R_v[qp,k,:]
// MFMA: A = attn[b, k] (bf16), B = R_v[k, d] (bf16, staged transposed).
// attn is 0 above the diagonal, so boundary tiles need no masking.
// Grid: (S qp).  Block: 256.
// ---------------------------------------------------------------------------
__global__ __launch_bounds__(256) void rvout_kernel(
    const float* __restrict__ Rv, const float* __restrict__ attn,
    float* outg) {
  const int qp = (S_ - 1) - (int)blockIdx.x;  // big rows first
  __shared__ __align__(16) ushort Ah[64 * 64];
  __shared__ __align__(16) ushort RvT[64 * 64];

  const int t = threadIdx.x;
  const int wid = t >> 6, lane = t & 63;
  const int llo = lane & 15, lhi = lane >> 4;
  const f32x4 fz = {0.f, 0.f, 0.f, 0.f};

  f32x4 oacc[4];
  #pragma unroll
  for (int nt = 0; nt < 4; ++nt) oacc[nt] = fz;

  const int ntiles = (qp >> 6) + 1;
  for (int tt = 0; tt < ntiles; ++tt) {
    const int kb = tt * 64;
    __syncthreads();
    #pragma unroll
    for (int i = 0; i < 4; ++i) {  // attn tile (coalesced rows)
      const int flat = t + i * 256;
      const int bb = flat >> 4, cc = (flat & 15) * 4;
      const float4 a4 =
          *(const float4*)(attn + (((bb << 10) + qp) << 10) + kb + cc);
      *(ushort4*)&Ah[SWZ(bb, cc)] =
          make_ushort4(f2bf(a4.x), f2bf(a4.y), f2bf(a4.z), f2bf(a4.w));
    }
    #pragma unroll
    for (int i = 0; i < 4; ++i) {  // R_v, transposed into RvT[d][k]
      const int kk = lane;
      const int dd = (wid + i * 4) * 4;
      const float4 r4 = *(const float4*)(Rv + (((qp << 10) + kb + kk) << 6) + dd);
      RvT[SWZ(dd + 0, kk)] = f2bf(r4.x);
      RvT[SWZ(dd + 1, kk)] = f2bf(r4.y);
      RvT[SWZ(dd + 2, kk)] = f2bf(r4.z);
      RvT[SWZ(dd + 3, kk)] = f2bf(r4.w);
    }
    __syncthreads();

    #pragma unroll
    for (int s = 0; s < 2; ++s) {
      const bf16x8 aa =
          *(const bf16x8*)&Ah[SWZ(wid * 16 + llo, s * 32 + lhi * 8)];
      #pragma unroll
      for (int nt = 0; nt < 4; ++nt) {
        const bf16x8 rb =
            *(const bf16x8*)&RvT[SWZ(nt * 16 + llo, s * 32 + lhi * 8)];
        oacc[nt] = MFMA(aa, rb, oacc[nt]);
      }
    }
  }

  #pragma unroll
  for (int r = 0; r < 4; ++r) {
    const int bb = wid * 16 + lhi * 4 + r;
    float* po = outg + (((bb << 10) + qp) << 6);
    #pragma unroll
    for (int nt = 0; nt < 4; ++nt) po[nt * 16 + llo] += oacc[nt][r];
  }
}

}  // namespace

extern "C" void kernel_launch(void* const* d_in, const int* in_sizes, int n_in,
                              void* d_out, int out_size, void* d_ws, size_t ws_size,
                              hipStream_t stream) {
  const float* q  = (const float*)d_in[0];
  const float* k  = (const float*)d_in[1];
  const float* v  = (const float*)d_in[2];
  const float* Rk = (const float*)d_in[3];
  const float* Rv = (const float*)d_in[4];
  // d_in[5] = mask (causal tril), d_in[6] = one_direction (==1): hardcoded.

  float* out  = (float*)d_out;
  float* attn = out + (size_t)B_ * S_ * D_;  // second output, also bias scratch

  hipLaunchKernelGGL(bias_kernel, dim3(4, S_), dim3(256), 0, stream, q, Rk, attn);
  hipLaunchKernelGGL(attn_kernel, dim3(16, B_), dim3(256), 0, stream, q, k, v, attn, out);
  hipLaunchKernelGGL(rvout_kernel, dim3(S_), dim3(256), 0, stream, Rv, attn, out);
}